// Round 3
// baseline (126.181 us; speedup 1.0000x reference)
//
#include <hip/hip_runtime.h>

#define D_MODEL 1024
#define KK 64
#define BSZ 16
#define CH 128          // d-elements per staged chunk
#define NCH 8           // D_MODEL / CH
#define LROW 65         // padded row stride (floats) of transposed LDS tile lds[d][j]

// ---------------------------------------------------------------------------
// Kernel A: one block (4 waves) per row r in [0, 1024).
//   P1[r][c] = sum_d Mp[r,d]*W[c,d]        -> P12[r*3+c]
//   P2[r][c] = sum_d Mp[r,d]*W[c,1024+d]   -> P12[3072 + r*3+c]
// ---------------------------------------------------------------------------
__global__ __launch_bounds__(256) void precompute_rows(
    const float* __restrict__ Mp, const float* __restrict__ W,
    float* __restrict__ P12)
{
    const int row  = blockIdx.x;           // 0..1023
    const int wid  = threadIdx.x >> 6;     // 0..3
    const int lane = threadIdx.x & 63;
    const int d    = wid * 256 + lane * 4;

    const float4 m = *reinterpret_cast<const float4*>(Mp + (size_t)row * D_MODEL + d);
    float s[6];
#pragma unroll
    for (int c = 0; c < 3; ++c) {
        const float4 w1 = *reinterpret_cast<const float4*>(W + c * 4096 + d);
        const float4 w2 = *reinterpret_cast<const float4*>(W + c * 4096 + 1024 + d);
        s[c]     = m.x * w1.x + m.y * w1.y + m.z * w1.z + m.w * w1.w;
        s[3 + c] = m.x * w2.x + m.y * w2.y + m.z * w2.z + m.w * w2.w;
    }
#pragma unroll
    for (int off = 32; off; off >>= 1)
#pragma unroll
        for (int t = 0; t < 6; ++t)
            s[t] += __shfl_xor(s[t], off, 64);

    __shared__ float part[4][6];
    if (lane == 0) {
#pragma unroll
        for (int t = 0; t < 6; ++t) part[wid][t] = s[t];
    }
    __syncthreads();
    if (threadIdx.x < 6) {
        const int t = threadIdx.x;
        const float v = part[0][t] + part[1][t] + part[2][t] + part[3][t];
        if (t < 3) P12[row * 3 + t]              = v;
        else       P12[3072 + row * 3 + (t - 3)] = v;
    }
}

// ---------------------------------------------------------------------------
// Kernel B: block = (b, i-pair). Grid 512 = 16 b x 32 itiles -> 2 blocks/CU.
// lane = j. mj comes from transposed LDS (conflict-free); mi, W3, W4 are
// wave-uniform -> scalar loads. Wave `uwid` handles d-quarter of each chunk
// for BOTH i's; 4-way partials combined via LDS at the end.
//   out[b,i,j,c] = P1[j,c] + P2[i,c] + sum_d |mi-mj|*W3[c,d] + mi*mj*W4[c,d]
// ---------------------------------------------------------------------------
__global__ __launch_bounds__(256, 2) void pair_kernel(
    const float* __restrict__ Mp, const float* __restrict__ W,
    const float* __restrict__ P12, float* __restrict__ out)
{
    __shared__ float lds[2][CH * LROW];   // 2 x 128x65 floats = 66,560 B

    const int b     = blockIdx.x >> 5;    // 0..15
    const int itile = blockIdx.x & 31;    // 0..31
    const int i0    = itile * 2;
    const int tid   = threadIdx.x;
    const int lane  = tid & 63;
    const int uwid  = __builtin_amdgcn_readfirstlane(tid >> 6);  // SGPR wave id

    const float* __restrict__ batch = Mp + (size_t)b * KK * D_MODEL;
    const float* __restrict__ rowi0 = batch + (size_t)i0 * D_MODEL;
    const float* __restrict__ rowi1 = rowi0 + D_MODEL;

    float acc[2][3] = {{0.f, 0.f, 0.f}, {0.f, 0.f, 0.f}};

    // ---- stage chunk 0 (transposed: lds[d][j]) ----
#pragma unroll
    for (int p = 0; p < 8; ++p) {
        const int idx  = p * 256 + tid;       // 0..2047
        const int row  = idx >> 5;            // j  0..63
        const int col4 = idx & 31;            // d-group 0..31
        const float4 v = *reinterpret_cast<const float4*>(batch + row * D_MODEL + col4 * 4);
        const int base = (col4 * 4) * LROW + row;
        lds[0][base]            = v.x;
        lds[0][base + LROW]     = v.y;
        lds[0][base + 2 * LROW] = v.z;
        lds[0][base + 3 * LROW] = v.w;
    }
    __syncthreads();

    for (int c = 0; c < NCH; ++c) {
        const int cur = c & 1;

        // issue next chunk's global loads early (regs), write to LDS late
        float4 stg[8];
        if (c + 1 < NCH) {
            const int d0n = (c + 1) * CH;
#pragma unroll
            for (int p = 0; p < 8; ++p) {
                const int idx  = p * 256 + tid;
                const int row  = idx >> 5;
                const int col4 = idx & 31;
                stg[p] = *reinterpret_cast<const float4*>(batch + row * D_MODEL + d0n + col4 * 4);
            }
        }

        // compute: this wave's 32-d slice of chunk c, both i's
        const int dbase = c * CH + uwid * 32;                   // uniform
        const float* __restrict__ w30 = W + 0 * 4096 + 2048 + dbase;
        const float* __restrict__ w31 = W + 1 * 4096 + 2048 + dbase;
        const float* __restrict__ w32 = W + 2 * 4096 + 2048 + dbase;
        const float* __restrict__ w40 = W + 0 * 4096 + 3072 + dbase;
        const float* __restrict__ w41 = W + 1 * 4096 + 3072 + dbase;
        const float* __restrict__ w42 = W + 2 * 4096 + 3072 + dbase;
        const float* __restrict__ mi0p = rowi0 + dbase;
        const float* __restrict__ mi1p = rowi1 + dbase;
        const float* __restrict__ ldsr = &lds[cur][(uwid * 32) * LROW + lane];

#pragma unroll
        for (int k = 0; k < 32; ++k) {
            const float mj  = ldsr[k * LROW];     // ds_read_b32, imm offset k*260
            const float mi0 = mi0p[k];            // uniform -> s_load
            const float mi1 = mi1p[k];
            const float a0 = w30[k], a1 = w31[k], a2 = w32[k];
            const float b0 = w40[k], b1 = w41[k], b2 = w42[k];

            const float df0 = fabsf(mi0 - mj);
            const float pr0 = mi0 * mj;
            acc[0][0] += df0 * a0;  acc[0][0] += pr0 * b0;
            acc[0][1] += df0 * a1;  acc[0][1] += pr0 * b1;
            acc[0][2] += df0 * a2;  acc[0][2] += pr0 * b2;

            const float df1 = fabsf(mi1 - mj);
            const float pr1 = mi1 * mj;
            acc[1][0] += df1 * a0;  acc[1][0] += pr1 * b0;
            acc[1][1] += df1 * a1;  acc[1][1] += pr1 * b1;
            acc[1][2] += df1 * a2;  acc[1][2] += pr1 * b2;
        }

        if (c + 1 < NCH) {
            float* dst = &lds[cur ^ 1][0];
#pragma unroll
            for (int p = 0; p < 8; ++p) {
                const int idx  = p * 256 + tid;
                const int row  = idx >> 5;
                const int col4 = idx & 31;
                const int base = (col4 * 4) * LROW + row;
                dst[base]            = stg[p].x;
                dst[base + LROW]     = stg[p].y;
                dst[base + 2 * LROW] = stg[p].z;
                dst[base + 3 * LROW] = stg[p].w;
            }
        }
        __syncthreads();
    }

    // ---- combine 4 wave-partials via LDS (reuse buffer 0) ----
    float* l2 = &lds[0][0];
#pragma unroll
    for (int ii = 0; ii < 2; ++ii)
#pragma unroll
        for (int cc = 0; cc < 3; ++cc)
            l2[((uwid * 2 + ii) * 3 + cc) * 64 + lane] = acc[ii][cc];
    __syncthreads();

    if (uwid < 2) {
        const int i = i0 + uwid;
#pragma unroll
        for (int cc = 0; cc < 3; ++cc) {
            const float s = l2[((0 * 2 + uwid) * 3 + cc) * 64 + lane]
                          + l2[((1 * 2 + uwid) * 3 + cc) * 64 + lane]
                          + l2[((2 * 2 + uwid) * 3 + cc) * 64 + lane]
                          + l2[((3 * 2 + uwid) * 3 + cc) * 64 + lane];
            const float v = s + P12[(b * 64 + lane) * 3 + cc]
                              + P12[3072 + (b * 64 + i) * 3 + cc];
            out[(((size_t)(b * 64 + i)) * 64 + lane) * 3 + cc] = v;
        }
    }
}

extern "C" void kernel_launch(void* const* d_in, const int* in_sizes, int n_in,
                              void* d_out, int out_size, void* d_ws, size_t ws_size,
                              hipStream_t stream)
{
    const float* Mp = (const float*)d_in[0];   // (16, 64, 1024) f32
    // d_in[1] = mask_p: unused by the reference (all-ones, never applied)
    const float* W  = (const float*)d_in[2];   // (3, 4096) f32
    float* out = (float*)d_out;                // (16, 64, 64, 3) f32
    float* P12 = (float*)d_ws;                 // 6144 floats scratch

    precompute_rows<<<1024, 256, 0, stream>>>(Mp, W, P12);
    pair_kernel<<<BSZ * 32, 256, 0, stream>>>(Mp, W, P12, out);
}